// Round 5
// baseline (135.374 us; speedup 1.0000x reference)
//
#include <hip/hip_runtime.h>

#define NUM_ENT 7
#define DIM_ENT 4
#define H 128            // NEMBED_HALF
#define OUTC (2 * H)     // 256 columns per entity
#define BPB 8            // batch elements per block (R10: back to 8)

typedef float f32x4 __attribute__((ext_vector_type(4)));   // native clang vector

// R10: occupancy + I-cache round. R9 measured VALUBusy 13%, HBM 19%,
// Occupancy 20% — latency-bound, every pipe idle. Fixes here:
//   1. 32 threads/elem again (8192 waves = 32 waves/CU potential) and
//      __launch_bounds__(256, 8) to force VGPR <= 64 so all 8 blocks/CU
//      are resident. LDS 896 B/block — no LDS cap.
//   2. Loops ROLLED (#pragma unroll 1) with entities re-read from LDS at
//      runtime index (broadcast ds_read_b128: free, no bank conflicts;
//      runtime-indexed VGPR arrays would scratch-spill, LDS doesn't).
//      Hot loop ~1 KB instead of the previous ~45 KB fully-unrolled body
//      that overflowed the 32 KB I-cache and had few waves to hide the
//      L2 instruction streaming.
//   3. Long-lived registers = weights only (wr[5]+br = 24 VGPRs in the rel
//      phase); prop phase runs first and releases its weights.
// j==i skip is a thread-uniform branch (i,j are loop counters, identical
// across the wave) -> s_cbranch, no divergence.
//
// Store pattern: half-wave (32 lanes, one batch elem) writes 32 x 16 B at
// stride 16 B = 512 B contiguous (4 full lines) per store instruction.
__global__ __launch_bounds__(256, 8) void ace_kernel(
    const float* __restrict__ ctx,     // [28, B]
    const float* __restrict__ w_prop,  // [4, 128]
    const float* __restrict__ b_prop,  // [128]
    const float* __restrict__ w_rel,   // [5, 128]
    const float* __restrict__ b_rel,   // [128]
    float* __restrict__ out,           // [B, 7, 256]
    int B)
{
    __shared__ float s_ents[BPB][NUM_ENT * DIM_ENT];          // 8 x 28 floats

    const int tid = threadIdx.x;
    const int b0 = blockIdx.x * BPB;

    // Stage ents, bb-fastest for coalescing: tid -> (k = tid>>3, bb = tid&7)
    if (tid < BPB * NUM_ENT * DIM_ENT) {                      // 224 threads
        const int k  = tid >> 3;
        const int bb = tid & 7;
        s_ents[bb][k] = ctx[(size_t)k * B + (b0 + bb)];
    }
    __syncthreads();

    const int w    = tid >> 6;
    const int lane = tid & 63;
    const int bb   = w * 2 + (lane >> 5);
    const int c4   = (lane & 31) << 2;
    float* outb = out + (size_t)(b0 + bb) * (NUM_ENT * OUTC);
    const float* se = &s_ents[bb][0];

    const f32x4 vzero = {0.f, 0.f, 0.f, 0.f};

    {   // ---- prop_emb: relu(ents @ w_prop + b_prop) -> cols c4
        const f32x4 wp0 = *(const f32x4*)(w_prop + 0 * H + c4);
        const f32x4 wp1 = *(const f32x4*)(w_prop + 1 * H + c4);
        const f32x4 wp2 = *(const f32x4*)(w_prop + 2 * H + c4);
        const f32x4 wp3 = *(const f32x4*)(w_prop + 3 * H + c4);
        const f32x4 bp  = *(const f32x4*)(b_prop + c4);
#pragma unroll 1
        for (int n = 0; n < NUM_ENT; ++n) {
            const f32x4 en = *(const f32x4*)(se + n * DIM_ENT);   // LDS broadcast
            f32x4 a = bp;
            a += en.x * wp0;
            a += en.y * wp1;
            a += en.z * wp2;
            a += en.w * wp3;
            a = __builtin_elementwise_max(a, vzero);
            *(f32x4*)(outb + n * OUTC + c4) = a;
        }
    }

    {   // ---- rel_emb: sum_{j!=i} relu(feat(i,j) @ w_rel + b_rel) -> cols 128+c4
        const f32x4 w0 = *(const f32x4*)(w_rel + 0 * H + c4);
        const f32x4 w1 = *(const f32x4*)(w_rel + 1 * H + c4);
        const f32x4 w2 = *(const f32x4*)(w_rel + 2 * H + c4);
        const f32x4 w3 = *(const f32x4*)(w_rel + 3 * H + c4);
        const f32x4 w4 = *(const f32x4*)(w_rel + 4 * H + c4);
        const f32x4 br = *(const f32x4*)(b_rel + c4);
#pragma unroll 1
        for (int i = 0; i < NUM_ENT; ++i) {
            const f32x4 ei = *(const f32x4*)(se + i * DIM_ENT);   // LDS broadcast
            f32x4 acc = vzero;
#pragma unroll 1
            for (int j = 0; j < NUM_ENT; ++j) {
                if (j == i) continue;                             // uniform branch
                const f32x4 ej = *(const f32x4*)(se + j * DIM_ENT);
                const float dx = ei.x - ej.x;
                const float dy = ei.y - ej.y;
                const float dz = ei.z - ej.z;
                const float dv = ei.w - ej.w;
                const float d  = __builtin_amdgcn_sqrtf(dx * dx + dy * dy);
                f32x4 t = br;
                t += dx * w0;
                t += dy * w1;
                t += dz * w2;
                t += dv * w3;
                t += d  * w4;
                acc += __builtin_elementwise_max(t, vzero);
            }
            *(f32x4*)(outb + i * OUTC + H + c4) = acc;
        }
    }
}

extern "C" void kernel_launch(void* const* d_in, const int* in_sizes, int n_in,
                              void* d_out, int out_size, void* d_ws, size_t ws_size,
                              hipStream_t stream) {
    const float* ctx    = (const float*)d_in[0];
    const float* w_prop = (const float*)d_in[1];
    const float* b_prop = (const float*)d_in[2];
    const float* w_rel  = (const float*)d_in[3];
    const float* b_rel  = (const float*)d_in[4];
    float* out = (float*)d_out;

    const int B = in_sizes[0] / (NUM_ENT * DIM_ENT);   // 16384
    const int nb = (B + BPB - 1) / BPB;                // 2048 blocks
    ace_kernel<<<nb, 256, 0, stream>>>(ctx, w_prop, b_prop, w_rel, b_rel, out, B);
}